// Round 14
// baseline (757.430 us; speedup 1.0000x reference)
//
#include <hip/hip_runtime.h>
#include <cstdint>
#include <cmath>

typedef _Float16 f16;
typedef _Float16 f16x8 __attribute__((ext_vector_type(8)));
typedef float f32x4 __attribute__((ext_vector_type(4)));

#define DEVI static __device__ __forceinline__

constexpr int B_ = 1024, S_ = 512, H_ = 2048, R_ = 64, G_ = 16, L_ = 4, A_ = 256;
constexpr float ADAPT = 0.1f;

// async global->LDS, 16B per lane. Dest is wave-uniform base + lane*16 (HW).
DEVI void gl_lds16(const void* g, void* l) {
  __builtin_amdgcn_global_load_lds((const __attribute__((address_space(1))) void*)g,
                                   (__attribute__((address_space(3))) void*)l,
                                   16, 0, 0);
}

template <int N> DEVI void wvc() {
  if constexpr (N == 0)       asm volatile("s_waitcnt vmcnt(0)");
  else if constexpr (N == 1)  asm volatile("s_waitcnt vmcnt(1)");
  else if constexpr (N == 2)  asm volatile("s_waitcnt vmcnt(2)");
  else if constexpr (N == 3)  asm volatile("s_waitcnt vmcnt(3)");
  else if constexpr (N == 4)  asm volatile("s_waitcnt vmcnt(4)");
  else if constexpr (N == 6)  asm volatile("s_waitcnt vmcnt(6)");
  else if constexpr (N == 8)  asm volatile("s_waitcnt vmcnt(8)");
  else if constexpr (N == 9)  asm volatile("s_waitcnt vmcnt(9)");
  else if constexpr (N == 12) asm volatile("s_waitcnt vmcnt(12)");
  else static_assert(N == 0, "unsupported vmcnt literal");
}

// ============================================================================
// prep_kernel: all input conversions in ONE launch.
// ============================================================================
DEVI void tr_body(float (*tile)[33], const float* __restrict__ src, f16* __restrict__ dst,
                  int rows, int cols, float scale, int bid) {
  const int nx = cols / 32, ny = rows / 32;
  const int z = bid / (nx * ny), rem = bid % (nx * ny);
  const int cy = rem / nx, cx = rem % nx;
  src += (size_t)z * rows * cols;
  dst += (size_t)z * rows * cols;
  const int tx = threadIdx.x, ty = threadIdx.y;
  const int r0 = cy * 32, c0 = cx * 32;
  #pragma unroll
  for (int i = ty; i < 32; i += 8)
    tile[i][tx] = src[(size_t)(r0 + i) * cols + (c0 + tx)];
  __syncthreads();
  #pragma unroll
  for (int i = ty; i < 32; i += 8)
    dst[(size_t)(c0 + i) * rows + (r0 + tx)] = (f16)(tile[tx][i] * scale);
}

__global__ void prep_kernel(const float* __restrict__ s, f16* __restrict__ sh,
                            const float* __restrict__ W_in, f16* __restrict__ Wint,
                            const float* __restrict__ W_main, f16* __restrict__ Wmt,
                            const float* __restrict__ Wa, f16* __restrict__ Wat,
                            const float* __restrict__ Wb, f16* __restrict__ Wbt,
                            const float* __restrict__ W_out, f16* __restrict__ Wot) {
  __shared__ float tile[32][33];
  int bid = blockIdx.x;
  if (bid < 2048) {               // cvt s: 1024*512 = 2048*256
    int i = bid * 256 + threadIdx.y * 32 + threadIdx.x;
    sh[i] = (f16)s[i];
    return;
  }
  bid -= 2048;
  if (bid < 1024)  { tr_body(tile, W_in,   Wint, S_, H_, 1.f,   bid); return; }
  bid -= 1024;
  if (bid < 16384) { tr_body(tile, W_main, Wmt,  H_, H_, 1.f,   bid); return; }
  bid -= 16384;
  if (bid < 8192)  { tr_body(tile, Wa,     Wat,  H_, R_, 1.f,   bid); return; }
  bid -= 8192;
  if (bid < 8192)  { tr_body(tile, Wb,     Wbt,  R_, H_, ADAPT, bid); return; }
  bid -= 8192;
  tr_body(tile, W_out, Wot, H_, A_, 1.f, bid);
}

// ============================================================================
// Shared macros
// ============================================================================
#define NOSTG ((void)0)
#define WV4 asm volatile("s_waitcnt vmcnt(4)")
#define WV0 asm volatile("s_waitcnt vmcnt(0)")
#define NOW ((void)0)
#define BAR() __builtin_amdgcn_s_barrier()
#define PRI1 __builtin_amdgcn_s_setprio(1)
#define PRI0 __builtin_amdgcn_s_setprio(0)

// ============================================================================
// CONTROL: 256x256 main GEMM — 3-phase tile, supertile swizzle (round-13).
// ============================================================================
#define MQ(QM, QN, AF, BF)                                                   \
  _Pragma("unroll") for (int i = 0; i < 4; ++i)                              \
  _Pragma("unroll") for (int j = 0; j < 2; ++j)                              \
  _Pragma("unroll") for (int k = 0; k < 2; ++k)                              \
    acc[QM][QN][i][j] = __builtin_amdgcn_mfma_f32_16x16x32_f16(              \
        AF[i][k], BF[j][k], acc[QM][QN][i][j], 0, 0, 0)

#define STGM(BASE, OFF, DST) do {                                            \
    gl_lds16(BASE + OFF, &lds[DST]);                                         \
    gl_lds16(BASE + OFF + 32768, &lds[DST + 1024]);                          \
    OFF += 128; DST ^= 65536; } while (0)
#define STGC(BASE, OFF, DST) do {                                            \
    gl_lds16(BASE + OFF, &lds[DST]);                                         \
    gl_lds16(BASE + OFF + 1024, &lds[DST + 1024]);                           \
    DST ^= 65536; } while (0)

#define TILE3(PC, S1a, S1b, S2a, S2b, BW) do {                               \
    f16x8 a0[4][2], a1[4][2], b0[2][2], b1v[2][2];                           \
    _Pragma("unroll") for (int i = 0; i < 4; ++i) {                          \
      a0[i][0] = *(const f16x8*)&lds[(PC) + cab + i * 2048 + lof0];          \
      a0[i][1] = *(const f16x8*)&lds[(PC) + cab + i * 2048 + lof1]; }        \
    _Pragma("unroll") for (int j = 0; j < 2; ++j) {                          \
      b0[j][0] = *(const f16x8*)&lds[(PC) + cbb + j * 2048 + lof0];          \
      b0[j][1] = *(const f16x8*)&lds[(PC) + cbb + j * 2048 + lof1]; }        \
    S1a; S1b; BAR();                                                         \
    PRI1; MQ(0, 0, a0, b0); PRI0; BAR();                                     \
    _Pragma("unroll") for (int j = 0; j < 2; ++j) {                          \
      b1v[j][0] = *(const f16x8*)&lds[(PC) + cbb + 16384 + j * 2048 + lof0]; \
      b1v[j][1] = *(const f16x8*)&lds[(PC) + cbb + 16384 + j * 2048 + lof1]; } \
    S2a; S2b; BAR();                                                         \
    PRI1; MQ(0, 1, a0, b1v); PRI0; BAR();                                    \
    _Pragma("unroll") for (int i = 0; i < 4; ++i) {                          \
      a1[i][0] = *(const f16x8*)&lds[(PC) + cab + 16384 + i * 2048 + lof0];  \
      a1[i][1] = *(const f16x8*)&lds[(PC) + cab + 16384 + i * 2048 + lof1]; } \
    BAR();                                                                   \
    PRI1; MQ(1, 1, a1, b1v); MQ(1, 0, a1, b0); PRI0;                         \
    BW; BAR();                                                               \
  } while (0)

__global__ __launch_bounds__(512, 2)
void gemm8_main_kernel(const f16* __restrict__ Aacts, const f16* __restrict__ Wm,
                       const f16* __restrict__ Z1, const f16* __restrict__ Wb2,
                       const float* __restrict__ b1, const float* __restrict__ b2,
                       f16* __restrict__ Out) {
  __shared__ __align__(16) char lds[131072];
  const int tid = threadIdx.x, lane = tid & 63, wid = tid >> 6;
  const int x = blockIdx.x & 7, local = blockIdx.x >> 3;
  const int bm0 = (x * 8 + (local & 7)) * 256, bn0 = (local >> 3) * 256;
  const int g = bm0 >> 10;
  const char* GA = (const char*)Aacts;
  const char* GB = (const char*)Wm;
  const char* GZ = (const char*)Z1;
  const char* GW2 = (const char*)(Wb2 + (size_t)g * H_ * R_);
  const float* b2g = b2 + (size_t)g * H_;

  const int srow8 = lane >> 3;
  const int scolb = ((lane & 7) ^ srow8) * 16;
  const int fr = lane & 15, fq = lane >> 4;
  const uint32_t lof0 = fr * 128 + ((fq * 16) ^ ((fr & 7) << 4));
  const uint32_t lof1 = lof0 ^ 64;

  const uint32_t rA0 = bm0 + wid * 16 + srow8;
  const uint32_t rB0 = bn0 + wid * 16 + srow8;
  uint32_t oA0 = rA0 * 4096 + scolb;
  uint32_t oA1 = oA0 + 128 * 4096;
  uint32_t oB0 = rB0 * 4096 + scolb;
  uint32_t oB1 = oB0 + 128 * 4096;
  uint32_t dA0 = wid * 2048;
  uint32_t dA1 = 16384 + wid * 2048;
  uint32_t dB0 = 32768 + wid * 2048;
  uint32_t dB1 = 49152 + wid * 2048;
  const uint32_t cab = (wid >> 2) * 8192;
  const uint32_t cbb = 32768 + (wid & 3) * 4096;

  f32x4 acc[2][2][4][2] = {};

  STGM(GA, oA0, dA0);
  STGM(GB, oB0, dB0);
  STGM(GA, oA1, dA1);
  STGM(GB, oB1, dB1);
  STGM(GA, oA0, dA0);
  STGM(GB, oB0, dB0);
  WV4;
  BAR();

  uint32_t oA0c = rA0 * 128 + scolb;
  uint32_t oA1c = oA0c + 128 * 128;
  uint32_t oB0c = rB0 * 128 + scolb;
  uint32_t oB1c = oB0c + 128 * 128;

  #pragma unroll 1
  for (int it = 0; it < 15; ++it) {
    TILE3(0,
          STGM(GB, oB1, dB1), STGM(GA, oA1, dA1),
          STGM(GA, oA0, dA0), STGM(GB, oB0, dB0), WV4);
    TILE3(65536,
          STGM(GB, oB1, dB1), STGM(GA, oA1, dA1),
          STGM(GA, oA0, dA0), STGM(GB, oB0, dB0), WV4);
  }
  TILE3(0,
        STGM(GB, oB1, dB1), STGM(GA, oA1, dA1),
        STGC(GZ, oA0c, dA0), STGC(GW2, oB0c, dB0), WV4);
  TILE3(65536,
        STGC(GW2, oB1c, dB1), STGC(GZ, oA1c, dA1),
        NOSTG, NOSTG, WV0);
  TILE3(0, NOSTG, NOSTG, NOSTG, NOSTG, NOW);

  #pragma unroll
  for (int Qn = 0; Qn < 2; ++Qn) {
    #pragma unroll
    for (int j = 0; j < 2; ++j) {
      const int col = bn0 + Qn * 128 + (wid & 3) * 32 + j * 16 + fr;
      const float bb1 = b1[col];
      const float bb2 = ADAPT * b2g[col];
      #pragma unroll
      for (int Qm = 0; Qm < 2; ++Qm)
        #pragma unroll
        for (int i = 0; i < 4; ++i)
          #pragma unroll
          for (int r = 0; r < 4; ++r) {
            const int row = bm0 + Qm * 128 + (wid >> 2) * 64 + i * 16 + fq * 4 + r;
            float v = acc[Qm][Qn][i][j][r] + bb1 + bb2;
            v = v > 0.f ? v : expm1f(v);
            Out[(size_t)row * H_ + col] = (f16)v;
          }
    }
  }
}

// ============================================================================
// CANDIDATE: 128x128 main GEMM, BK=64, 4 waves, 64 KiB LDS -> 2 blocks/CU.
// Bet: cross-block overlap (m114) — when one block's waves sit at barrier/
// vmcnt, the co-resident block's waves feed the MFMA pipe.
// Staging safety: B(u+1) in P1 (other parity; tenant consumed pre tile-u
// entry barrier); A(u+2) after post-Q1 barrier (tenant af(u) consumed by
// Q1's lgkm wait, ordered by that barrier). WV4/tile retires tile u+1.
// ============================================================================
#define SG4(BASE, OFF, DST) do {                                             \
    gl_lds16(BASE + OFF, &lds[DST]);                                         \
    gl_lds16(BASE + OFF + 32768, &lds[DST + 1024]);                          \
    gl_lds16(BASE + OFF + 65536, &lds[DST + 2048]);                          \
    gl_lds16(BASE + OFF + 98304, &lds[DST + 3072]);                          \
    OFF += 128; DST ^= 32768; } while (0)
#define SG4C(BASE, OFF, DST) do {                                            \
    gl_lds16(BASE + OFF, &lds[DST]);                                         \
    gl_lds16(BASE + OFF + 1024, &lds[DST + 1024]);                           \
    gl_lds16(BASE + OFF + 2048, &lds[DST + 2048]);                           \
    gl_lds16(BASE + OFF + 3072, &lds[DST + 3072]);                           \
    DST ^= 32768; } while (0)

#define T128(PC, SB1, SA2, BW) do {                                          \
    f16x8 af[4][2], bf[4][2];                                                \
    _Pragma("unroll") for (int i = 0; i < 4; ++i) {                          \
      af[i][0] = *(const f16x8*)&lds[(PC) + cab + i * 2048 + lof0];          \
      af[i][1] = *(const f16x8*)&lds[(PC) + cab + i * 2048 + lof1]; }        \
    _Pragma("unroll") for (int j = 0; j < 2; ++j) {                          \
      bf[j][0] = *(const f16x8*)&lds[(PC) + cbb + j * 2048 + lof0];          \
      bf[j][1] = *(const f16x8*)&lds[(PC) + cbb + j * 2048 + lof1]; }        \
    SB1;                                                                     \
    PRI1;                                                                    \
    _Pragma("unroll") for (int i = 0; i < 4; ++i)                            \
    _Pragma("unroll") for (int j = 0; j < 2; ++j)                            \
    _Pragma("unroll") for (int k = 0; k < 2; ++k)                            \
      acc[i][j] = __builtin_amdgcn_mfma_f32_16x16x32_f16(                    \
          af[i][k], bf[j][k], acc[i][j], 0, 0, 0);                           \
    PRI0; BAR();                                                             \
    _Pragma("unroll") for (int j = 2; j < 4; ++j) {                          \
      bf[j][0] = *(const f16x8*)&lds[(PC) + cbb + j * 2048 + lof0];          \
      bf[j][1] = *(const f16x8*)&lds[(PC) + cbb + j * 2048 + lof1]; }        \
    SA2;                                                                     \
    PRI1;                                                                    \
    _Pragma("unroll") for (int i = 0; i < 4; ++i)                            \
    _Pragma("unroll") for (int j = 2; j < 4; ++j)                            \
    _Pragma("unroll") for (int k = 0; k < 2; ++k)                            \
      acc[i][j] = __builtin_amdgcn_mfma_f32_16x16x32_f16(                    \
          af[i][k], bf[j][k], acc[i][j], 0, 0, 0);                           \
    PRI0; BW; BAR();                                                         \
  } while (0)

__global__ __launch_bounds__(256, 2)
void gemm128_main_kernel(const f16* __restrict__ Aacts, const f16* __restrict__ Wm,
                         const f16* __restrict__ Z1, const f16* __restrict__ Wb2,
                         const float* __restrict__ b1, const float* __restrict__ b2,
                         f16* __restrict__ Out) {
  __shared__ __align__(16) char lds[65536];
  const int tid = threadIdx.x, lane = tid & 63, wid = tid >> 6;
  // supertile: XCD x owns bm blocks [16x, 16x+16), bn sweeps slowest
  const int x = blockIdx.x & 7, local = blockIdx.x >> 3;
  const int bm0 = (x * 16 + (local & 15)) * 128, bn0 = (local >> 4) * 128;
  const int g = bm0 >> 10;
  const char* GA = (const char*)Aacts;
  const char* GB = (const char*)Wm;
  const char* GZ = (const char*)Z1;
  const char* GW2 = (const char*)(Wb2 + (size_t)g * H_ * R_);
  const float* b2g = b2 + (size_t)g * H_;

  const int srow8 = lane >> 3;
  const int scolb = ((lane & 7) ^ srow8) * 16;
  const int fr = lane & 15, fq = lane >> 4;
  const uint32_t lof0 = fr * 128 + ((fq * 16) ^ ((fr & 7) << 4));
  const uint32_t lof1 = lof0 ^ 64;

  const uint32_t rA = bm0 + wid * 32 + srow8;
  const uint32_t rB = bn0 + wid * 32 + srow8;
  uint32_t oA = rA * 4096 + scolb;
  uint32_t oB = rB * 4096 + scolb;
  uint32_t dA = wid * 4096;
  uint32_t dB = 16384 + wid * 4096;
  const uint32_t cab = (wid >> 1) * 8192;          // wave M-offset (64 rows)
  const uint32_t cbb = 16384 + (wid & 1) * 8192;   // wave N-offset (64 cols)

  f32x4 acc[4][4] = {};

  // prologue: A(0), B(0), A(1) = 12 loads; retire A0,B0 (leave A1 in flight)
  SG4(GA, oA, dA);
  SG4(GB, oB, dB);
  SG4(GA, oA, dA);
  WV4;
  BAR();

  uint32_t oAc = rA * 128 + scolb;
  uint32_t oBc = rB * 128 + scolb;

  // steady: tiles 0..29; P1 stages B(u+1), P2 stages A(u+2)
  #pragma unroll 1
  for (int it = 0; it < 15; ++it) {
    T128(0,     SG4(GB, oB, dB), SG4(GA, oA, dA), WV4);
    T128(32768, SG4(GB, oB, dB), SG4(GA, oA, dA), WV4);
  }
  // u=30: B(31) main; A(32) = concat (Z1, 128B rows)
  T128(0,     SG4(GB, oB, dB), SG4C(GZ, oAc, dA), WV4);
  // u=31: B(32) = concat (0.1*Wb^T); drain all
  T128(32768, SG4C(GW2, oBc, dB), NOSTG, WV0);
  // u=32: concat compute only
  T128(0, NOSTG, NOSTG, NOW);

  // epilogue
  #pragma unroll
  for (int j = 0; j < 4; ++j) {
    const int col = bn0 + (wid & 1) * 64 + j * 16 + fr;
    const float bb1 = b1[col];
    const float bb2 = ADAPT * b2g[col];
    #pragma unroll
    for (int i = 0; i < 4; ++i)
      #pragma unroll
      for (int r = 0; r < 4; ++r) {
        const int row = bm0 + (wid >> 1) * 64 + i * 16 + fq * 4 + r;
        float v = acc[i][j][r] + bb1 + bb2;
        v = v > 0.f ? v : expm1f(v);
        Out[(size_t)row * H_ + col] = (f16)v;
      }
  }
}

enum { EPI_Z1 = 0, EPI_OUT = 1, EPI_L0 = 2 };

// ============================================================================
// Small/odd-shape GEMM with 4-deep ring-buffer pipeline (counted vmcnt). BK=32.
// ============================================================================
template <int BM, int BN, int WM, int WN, int EPI>
__global__ __launch_bounds__((BM / WM) * (BN / WN) * 64)
void gemm_db_kernel(const f16* __restrict__ A, long long lda, long long Az,
                    const f16* __restrict__ Bw, long long ldb, long long Bz,
                    long long Bg, int NT,
                    const float* __restrict__ bias1, long long b1z,
                    const float* __restrict__ bias2, long long b2z,
                    const f16* __restrict__ addmat,
                    void* __restrict__ outp, long long out_z, long long ldo,
                    int rows_per_group) {
  constexpr int NW = (BM / WM) * (BN / WN);
  constexpr int FM = WM / 16, FN = WN / 16;
  constexpr int RA = BM / (NW * 16), RB = BN / (NW * 16);
  constexpr int LPT = RA + RB;
  const int tid = threadIdx.x, lane = tid & 63, wid = tid >> 6;
  const int bm0 = blockIdx.x * BM, bn0 = blockIdx.y * BN;
  const int z = blockIdx.z;
  const int gidx = (rows_per_group > 0) ? (bm0 / rows_per_group) : 0;

  __shared__ __align__(16) f16 As[4][BM * 32];
  __shared__ __align__(16) f16 Bs[4][BN * 32];

  const int wm0 = (wid / (BN / WN)) * WM;
  const int wn0 = (wid % (BN / WN)) * WN;
  const int srow = wid * 16 + (lane >> 2);
  const int scol = (lane & 3) * 8;
  const int fr = lane & 15, fq = lane >> 4;

  const f16* pa = A + (long long)z * Az + (long long)(bm0 + srow) * lda + scol;
  const f16* pb = Bw + (long long)z * Bz + (long long)gidx * Bg +
                  (long long)(bn0 + srow) * ldb + scol;
  const long long stA = (long long)(NW * 16) * lda;
  const long long stB = (long long)(NW * 16) * ldb;

  f32x4 acc[FM][FN] = {};

  auto stage = [&](int t) {
    const f16* qa = pa + t * 32;
    const f16* qb = pb + t * 32;
    const int b = t & 3;
    #pragma unroll
    for (int r = 0; r < RA; ++r)
      gl_lds16(qa + r * stA, &As[b][(r * NW + wid) * 512]);
    #pragma unroll
    for (int r = 0; r < RB; ++r)
      gl_lds16(qb + r * stB, &Bs[b][(r * NW + wid) * 512]);
  };
  auto comp = [&](int t) {
    const int b = t & 3;
    f16x8 af[FM], bf[FN];
    #pragma unroll
    for (int i = 0; i < FM; ++i)
      af[i] = *(const f16x8*)&As[b][(wm0 + i * 16 + fr) * 32 + fq * 8];
    #pragma unroll
    for (int j = 0; j < FN; ++j)
      bf[j] = *(const f16x8*)&Bs[b][(wn0 + j * 16 + fr) * 32 + fq * 8];
    #pragma unroll
    for (int i = 0; i < FM; ++i)
      #pragma unroll
      for (int j = 0; j < FN; ++j)
        acc[i][j] = __builtin_amdgcn_mfma_f32_16x16x32_f16(af[i], bf[j], acc[i][j], 0, 0, 0);
  };

  if (NT <= 4) {
    for (int t = 0; t < NT; ++t) stage(t);
    wvc<0>();
    BAR();
    for (int t = 0; t < NT; ++t) comp(t);
  } else {
    stage(0); stage(1); stage(2); stage(3);
    int t = 0;
    #pragma unroll 1
    for (; t < NT - 4; ++t) {
      wvc<3 * LPT>();
      BAR();
      comp(t);
      BAR();
      stage(t + 4);
    }
    wvc<3 * LPT>(); BAR(); comp(t); BAR(); ++t;
    wvc<2 * LPT>(); BAR(); comp(t); BAR(); ++t;
    wvc<1 * LPT>(); BAR(); comp(t); BAR(); ++t;
    wvc<0>();       BAR(); comp(t);
  }

  const float* b1p = bias1 ? bias1 + (long long)z * b1z : nullptr;
  const float* b2p = bias2 ? bias2 + (long long)gidx * b2z : nullptr;
  #pragma unroll
  for (int i = 0; i < FM; ++i) {
    #pragma unroll
    for (int j = 0; j < FN; ++j) {
      const int col = bn0 + wn0 + j * 16 + fr;
      const float b1 = b1p ? b1p[col] : 0.f;
      const float b2v = b2p ? ADAPT * b2p[col] : 0.f;
      #pragma unroll
      for (int r = 0; r < 4; ++r) {
        const int row = bm0 + wm0 + i * 16 + fq * 4 + r;
        float v = acc[i][j][r] + b1 + b2v;
        if constexpr (EPI == EPI_L0) {
          v += (float)addmat[(long long)(row & (B_ - 1)) * H_ + col];
          v = v > 0.f ? v : expm1f(v);
          ((f16*)outp)[(long long)row * ldo + col] = (f16)v;
        } else if constexpr (EPI == EPI_Z1) {
          ((f16*)outp)[(long long)z * out_z + (long long)row * ldo + col] = (f16)v;
        } else {  // EPI_OUT: group-major row -> [B, G, A] fp32
          const int g = row >> 10, b = row & 1023;
          ((float*)outp)[((long long)b * G_ + g) * A_ + col] = v;
        }
      }
    }
  }
}

extern "C" void kernel_launch(void* const* d_in, const int* in_sizes, int n_in,
                              void* d_out, int out_size, void* d_ws, size_t ws_size,
                              hipStream_t stream) {
  const float* s      = (const float*)d_in[0];
  const float* W_in   = (const float*)d_in[1];
  const float* b_in   = (const float*)d_in[2];
  const float* W_main = (const float*)d_in[3];
  const float* b_main = (const float*)d_in[4];
  const float* Wa     = (const float*)d_in[5];
  const float* ba     = (const float*)d_in[6];
  const float* Wb     = (const float*)d_in[7];
  const float* bb     = (const float*)d_in[8];
  const float* W_out  = (const float*)d_in[9];
  const float* b_out  = (const float*)d_in[10];

  char* ws = (char*)d_ws;
  size_t off = 0;
  auto alloc = [&](size_t bytes) -> void* {
    void* p = ws + off;
    off += (bytes + 255) & ~(size_t)255;
    return p;
  };
  f16* sh   = (f16*)alloc((size_t)B_ * S_ * 2);
  f16* Wint = (f16*)alloc((size_t)H_ * S_ * 2);
  f16* Wmt  = (f16*)alloc((size_t)L_ * H_ * H_ * 2);
  f16* Wat  = (f16*)alloc((size_t)L_ * G_ * R_ * H_ * 2);
  f16* Wbt  = (f16*)alloc((size_t)L_ * G_ * H_ * R_ * 2);
  f16* Wot  = (f16*)alloc((size_t)A_ * H_ * 2);
  f16* xh0  = (f16*)alloc((size_t)G_ * B_ * H_ * 2);
  f16* xh1  = (f16*)alloc((size_t)G_ * B_ * H_ * 2);
  f16* z1h  = (f16*)alloc((size_t)G_ * B_ * R_ * 2);
  f16* x0h  = xh1;                     // aliases: dead before xh1 first written
  f16* y0h  = xh1 + (size_t)B_ * H_;

  // all conversions/transposes in ONE launch
  prep_kernel<<<36352, dim3(32, 8), 0, stream>>>(
      s, sh, W_in, Wint, W_main, Wmt, Wa, Wat, Wb, Wbt, W_out, Wot);

  // x0 = s @ W_in + b_in  [B, H]
  gemm_db_kernel<32, 64, 32, 32, EPI_Z1><<<dim3(B_ / 32, H_ / 64, 1), 128, 0, stream>>>(
      sh, S_, 0, Wint, S_, 0, 0, S_ / 32,
      b_in, 0, nullptr, 0, nullptr, x0h, 0, H_, 0);

  // y0 = x0 @ W_main[0] + b_main[0]  [B, H]
  gemm_db_kernel<32, 64, 32, 32, EPI_Z1><<<dim3(B_ / 32, H_ / 64, 1), 128, 0, stream>>>(
      x0h, H_, 0, Wmt, H_, 0, 0, H_ / 32,
      b_main, 0, nullptr, 0, nullptr, y0h, 0, H_, 0);

  // layer-0 z1[g] = x0 @ Wa[0,g] + ba[0,g]
  gemm_db_kernel<32, 64, 32, 32, EPI_Z1><<<dim3(B_ / 32, 1, G_), 128, 0, stream>>>(
      x0h, H_, 0, Wat, H_, (long long)R_ * H_, 0, H_ / 32,
      ba, R_, nullptr, 0, nullptr, z1h, (long long)B_ * R_, R_, 0);

  // layer-0 combine: x1 = elu(y0 + z1 @ (0.1*Wb[0,g]) + 0.1*bb[0,g]) -> [G,B,H]
  gemm_db_kernel<64, 128, 32, 64, EPI_L0><<<dim3(G_ * B_ / 64, H_ / 128, 1), 256, 0, stream>>>(
      z1h, R_, 0, Wbt, R_, 0, (long long)H_ * R_, R_ / 32,
      nullptr, 0, bb, H_, y0h, xh0, 0, H_, B_);

  f16* cur = xh0;
  f16* nxt = xh1;
  for (int l = 1; l < L_; ++l) {
    gemm_db_kernel<32, 64, 32, 32, EPI_Z1><<<dim3(B_ / 32, 1, G_), 128, 0, stream>>>(
        cur, H_, (long long)B_ * H_,
        Wat + (size_t)l * G_ * R_ * H_, H_, (long long)R_ * H_, 0, H_ / 32,
        ba + (size_t)l * G_ * R_, R_, nullptr, 0, nullptr,
        z1h, (long long)B_ * R_, R_, 0);
    // A/B: layers 1,3 -> 128^2 2-blocks/CU candidate; layer 2 -> 256^2 control
    if (l == 2)
      gemm8_main_kernel<<<512, 512, 0, stream>>>(
          cur, Wmt + (size_t)l * H_ * H_, z1h, Wbt + (size_t)l * G_ * H_ * R_,
          b_main + (size_t)l * H_, bb + (size_t)l * G_ * H_, nxt);
    else
      gemm128_main_kernel<<<2048, 256, 0, stream>>>(
          cur, Wmt + (size_t)l * H_ * H_, z1h, Wbt + (size_t)l * G_ * H_ * R_,
          b_main + (size_t)l * H_, bb + (size_t)l * G_ * H_, nxt);
    f16* t = cur; cur = nxt; nxt = t;
  }

  // output: logits[b,g,:] = x @ W_out + b_out (fp32, permuted store)
  gemm_db_kernel<64, 128, 32, 64, EPI_OUT><<<dim3(G_ * B_ / 64, A_ / 128, 1), 256, 0, stream>>>(
      cur, H_, 0, Wot, H_, 0, 0, H_ / 32,
      b_out, 0, nullptr, 0, nullptr, d_out, 0, A_, 0);
}

// Round 16
// 702.627 us; speedup vs baseline: 1.0780x; 1.0780x over previous
//
#include <hip/hip_runtime.h>
#include <cstdint>
#include <cmath>

typedef _Float16 f16;
typedef _Float16 f16x8 __attribute__((ext_vector_type(8)));
typedef float f32x4 __attribute__((ext_vector_type(4)));

#define DEVI static __device__ __forceinline__

constexpr int B_ = 1024, S_ = 512, H_ = 2048, R_ = 64, G_ = 16, L_ = 4, A_ = 256;
constexpr float ADAPT = 0.1f;

// async global->LDS, 16B per lane. Dest is wave-uniform base + lane*16 (HW).
DEVI void gl_lds16(const void* g, void* l) {
  __builtin_amdgcn_global_load_lds((const __attribute__((address_space(1))) void*)g,
                                   (__attribute__((address_space(3))) void*)l,
                                   16, 0, 0);
}

template <int N> DEVI void wvc() {
  if constexpr (N == 0)       asm volatile("s_waitcnt vmcnt(0)");
  else if constexpr (N == 1)  asm volatile("s_waitcnt vmcnt(1)");
  else if constexpr (N == 2)  asm volatile("s_waitcnt vmcnt(2)");
  else if constexpr (N == 3)  asm volatile("s_waitcnt vmcnt(3)");
  else if constexpr (N == 4)  asm volatile("s_waitcnt vmcnt(4)");
  else if constexpr (N == 6)  asm volatile("s_waitcnt vmcnt(6)");
  else if constexpr (N == 8)  asm volatile("s_waitcnt vmcnt(8)");
  else if constexpr (N == 9)  asm volatile("s_waitcnt vmcnt(9)");
  else if constexpr (N == 12) asm volatile("s_waitcnt vmcnt(12)");
  else static_assert(N == 0, "unsupported vmcnt literal");
}

// ============================================================================
// prep_kernel: all input conversions in ONE launch.
// ============================================================================
DEVI void tr_body(float (*tile)[33], const float* __restrict__ src, f16* __restrict__ dst,
                  int rows, int cols, float scale, int bid) {
  const int nx = cols / 32, ny = rows / 32;
  const int z = bid / (nx * ny), rem = bid % (nx * ny);
  const int cy = rem / nx, cx = rem % nx;
  src += (size_t)z * rows * cols;
  dst += (size_t)z * rows * cols;
  const int tx = threadIdx.x, ty = threadIdx.y;
  const int r0 = cy * 32, c0 = cx * 32;
  #pragma unroll
  for (int i = ty; i < 32; i += 8)
    tile[i][tx] = src[(size_t)(r0 + i) * cols + (c0 + tx)];
  __syncthreads();
  #pragma unroll
  for (int i = ty; i < 32; i += 8)
    dst[(size_t)(c0 + i) * rows + (r0 + tx)] = (f16)(tile[tx][i] * scale);
}

__global__ void prep_kernel(const float* __restrict__ s, f16* __restrict__ sh,
                            const float* __restrict__ W_in, f16* __restrict__ Wint,
                            const float* __restrict__ W_main, f16* __restrict__ Wmt,
                            const float* __restrict__ Wa, f16* __restrict__ Wat,
                            const float* __restrict__ Wb, f16* __restrict__ Wbt,
                            const float* __restrict__ W_out, f16* __restrict__ Wot) {
  __shared__ float tile[32][33];
  int bid = blockIdx.x;
  if (bid < 2048) {               // cvt s: 1024*512 = 2048*256
    int i = bid * 256 + threadIdx.y * 32 + threadIdx.x;
    sh[i] = (f16)s[i];
    return;
  }
  bid -= 2048;
  if (bid < 1024)  { tr_body(tile, W_in,   Wint, S_, H_, 1.f,   bid); return; }
  bid -= 1024;
  if (bid < 16384) { tr_body(tile, W_main, Wmt,  H_, H_, 1.f,   bid); return; }
  bid -= 16384;
  if (bid < 8192)  { tr_body(tile, Wa,     Wat,  H_, R_, 1.f,   bid); return; }
  bid -= 8192;
  if (bid < 8192)  { tr_body(tile, Wb,     Wbt,  R_, H_, ADAPT, bid); return; }
  bid -= 8192;
  tr_body(tile, W_out, Wot, H_, A_, 1.f, bid);
}

// ============================================================================
// Main 256x256 GEMM — 3-phase tile, supertile XCD swizzle (FETCH 281->103 MB).
//   Out = elu( Aacts[16384,2048] @ Wm^T + b1 + Z1[16384,64] @ (0.1*Wb)^T + 0.1*b2 )
// FROZEN: best measured 155 us; overlap rewrites regress (compiler lgkm).
// ============================================================================
#define MQ(QM, QN, AF, BF)                                                   \
  _Pragma("unroll") for (int i = 0; i < 4; ++i)                              \
  _Pragma("unroll") for (int j = 0; j < 2; ++j)                              \
  _Pragma("unroll") for (int k = 0; k < 2; ++k)                              \
    acc[QM][QN][i][j] = __builtin_amdgcn_mfma_f32_16x16x32_f16(              \
        AF[i][k], BF[j][k], acc[QM][QN][i][j], 0, 0, 0)

#define STGM(BASE, OFF, DST) do {                                            \
    gl_lds16(BASE + OFF, &lds[DST]);                                         \
    gl_lds16(BASE + OFF + 32768, &lds[DST + 1024]);                          \
    OFF += 128; DST ^= 65536; } while (0)
#define STGC(BASE, OFF, DST) do {                                            \
    gl_lds16(BASE + OFF, &lds[DST]);                                         \
    gl_lds16(BASE + OFF + 1024, &lds[DST + 1024]);                           \
    DST ^= 65536; } while (0)
#define NOSTG ((void)0)
#define WV4 asm volatile("s_waitcnt vmcnt(4)")
#define WV0 asm volatile("s_waitcnt vmcnt(0)")
#define NOW ((void)0)
#define BAR() __builtin_amdgcn_s_barrier()
#define PRI1 __builtin_amdgcn_s_setprio(1)
#define PRI0 __builtin_amdgcn_s_setprio(0)

#define TILE3(PC, S1a, S1b, S2a, S2b, BW) do {                               \
    f16x8 a0[4][2], a1[4][2], b0[2][2], b1v[2][2];                           \
    _Pragma("unroll") for (int i = 0; i < 4; ++i) {                          \
      a0[i][0] = *(const f16x8*)&lds[(PC) + cab + i * 2048 + lof0];          \
      a0[i][1] = *(const f16x8*)&lds[(PC) + cab + i * 2048 + lof1]; }        \
    _Pragma("unroll") for (int j = 0; j < 2; ++j) {                          \
      b0[j][0] = *(const f16x8*)&lds[(PC) + cbb + j * 2048 + lof0];          \
      b0[j][1] = *(const f16x8*)&lds[(PC) + cbb + j * 2048 + lof1]; }        \
    S1a; S1b; BAR();                                                         \
    PRI1; MQ(0, 0, a0, b0); PRI0; BAR();                                     \
    _Pragma("unroll") for (int j = 0; j < 2; ++j) {                          \
      b1v[j][0] = *(const f16x8*)&lds[(PC) + cbb + 16384 + j * 2048 + lof0]; \
      b1v[j][1] = *(const f16x8*)&lds[(PC) + cbb + 16384 + j * 2048 + lof1]; } \
    S2a; S2b; BAR();                                                         \
    PRI1; MQ(0, 1, a0, b1v); PRI0; BAR();                                    \
    _Pragma("unroll") for (int i = 0; i < 4; ++i) {                          \
      a1[i][0] = *(const f16x8*)&lds[(PC) + cab + 16384 + i * 2048 + lof0];  \
      a1[i][1] = *(const f16x8*)&lds[(PC) + cab + 16384 + i * 2048 + lof1]; } \
    BAR();                                                                   \
    PRI1; MQ(1, 1, a1, b1v); MQ(1, 0, a1, b0); PRI0;                         \
    BW; BAR();                                                               \
  } while (0)

__global__ __launch_bounds__(512, 2)
void gemm8_main_kernel(const f16* __restrict__ Aacts,   // [16384][2048]
                      const f16* __restrict__ Wm,       // [2048][2048] W_main^T
                      const f16* __restrict__ Z1,       // [16384][64]
                      const f16* __restrict__ Wb2,      // [G][2048][64] 0.1*Wb^T
                      const float* __restrict__ b1,     // [2048]
                      const float* __restrict__ b2,     // [G][2048]
                      f16* __restrict__ Out) {          // [16384][2048]
  __shared__ __align__(16) char lds[131072];
  const int tid = threadIdx.x, lane = tid & 63, wid = tid >> 6;
  // supertile: XCD x owns bm in [8x, 8x+8), all bn -> per-XCD set A 8MB + W 4MB
  const int x = blockIdx.x & 7, local = blockIdx.x >> 3;
  const int bm0 = (x * 8 + (local & 7)) * 256, bn0 = (local >> 3) * 256;
  const int g = bm0 >> 10;
  const char* GA = (const char*)Aacts;
  const char* GB = (const char*)Wm;
  const char* GZ = (const char*)Z1;
  const char* GW2 = (const char*)(Wb2 + (size_t)g * H_ * R_);
  const float* b2g = b2 + (size_t)g * H_;

  const int srow8 = lane >> 3;
  const int scolb = ((lane & 7) ^ srow8) * 16;
  const int fr = lane & 15, fq = lane >> 4;
  const uint32_t lof0 = fr * 128 + ((fq * 16) ^ ((fr & 7) << 4));
  const uint32_t lof1 = lof0 ^ 64;

  const uint32_t rA0 = bm0 + wid * 16 + srow8;
  const uint32_t rB0 = bn0 + wid * 16 + srow8;
  uint32_t oA0 = rA0 * 4096 + scolb;
  uint32_t oA1 = oA0 + 128 * 4096;
  uint32_t oB0 = rB0 * 4096 + scolb;
  uint32_t oB1 = oB0 + 128 * 4096;
  uint32_t dA0 = wid * 2048;
  uint32_t dA1 = 16384 + wid * 2048;
  uint32_t dB0 = 32768 + wid * 2048;
  uint32_t dB1 = 49152 + wid * 2048;
  const uint32_t cab = (wid >> 2) * 8192;
  const uint32_t cbb = 32768 + (wid & 3) * 4096;

  f32x4 acc[2][2][4][2] = {};   // [Qm][Qn][i][j]

  // prologue: tile0 full (A0,B0,A1,B1) + tile1's A0,B0 = 12 loads; retire tile0.
  STGM(GA, oA0, dA0);
  STGM(GB, oB0, dB0);
  STGM(GA, oA1, dA1);
  STGM(GB, oB1, dB1);
  STGM(GA, oA0, dA0);
  STGM(GB, oB0, dB0);
  WV4;
  BAR();

  uint32_t oA0c = rA0 * 128 + scolb;
  uint32_t oA1c = oA0c + 128 * 128;
  uint32_t oB0c = rB0 * 128 + scolb;
  uint32_t oB1c = oB0c + 128 * 128;

  // steady: tiles 0..29
  #pragma unroll 1
  for (int it = 0; it < 15; ++it) {
    TILE3(0,
          STGM(GB, oB1, dB1), STGM(GA, oA1, dA1),
          STGM(GA, oA0, dA0), STGM(GB, oB0, dB0), WV4);
    TILE3(65536,
          STGM(GB, oB1, dB1), STGM(GA, oA1, dA1),
          STGM(GA, oA0, dA0), STGM(GB, oB0, dB0), WV4);
  }
  // t=30: P1 stages B1/A1(31) main; P2 stages A0/B0(32) = concat (128B rows)
  TILE3(0,
        STGM(GB, oB1, dB1), STGM(GA, oA1, dA1),
        STGC(GZ, oA0c, dA0), STGC(GW2, oB0c, dB0), WV4);
  // t=31: P1 stages B1/A1(32) concat; drain all at end
  TILE3(65536,
        STGC(GW2, oB1c, dB1), STGC(GZ, oA1c, dA1),
        NOSTG, NOSTG, WV0);
  // t=32: concat compute only
  TILE3(0, NOSTG, NOSTG, NOSTG, NOSTG, NOW);

  // epilogue: v = acc + b1[col] + 0.1*b2[col]; ELU; f16 store
  #pragma unroll
  for (int Qn = 0; Qn < 2; ++Qn) {
    #pragma unroll
    for (int j = 0; j < 2; ++j) {
      const int col = bn0 + Qn * 128 + (wid & 3) * 32 + j * 16 + fr;
      const float bb1 = b1[col];
      const float bb2 = ADAPT * b2g[col];
      #pragma unroll
      for (int Qm = 0; Qm < 2; ++Qm)
        #pragma unroll
        for (int i = 0; i < 4; ++i)
          #pragma unroll
          for (int r = 0; r < 4; ++r) {
            const int row = bm0 + Qm * 128 + (wid >> 2) * 64 + i * 16 + fq * 4 + r;
            float v = acc[Qm][Qn][i][j][r] + bb1 + bb2;
            v = v > 0.f ? v : expm1f(v);
            Out[(size_t)row * H_ + col] = (f16)v;
          }
    }
  }
}

enum { EPI_Z1 = 0, EPI_OUT = 1, EPI_L0 = 2 };

// ============================================================================
// Small/odd-shape GEMM with 4-deep ring-buffer pipeline (counted vmcnt). BK=32.
// TLP discipline: keep >=2 blocks/CU (small BM, small LDS) so one block's
// vmcnt+barrier waits hide under another's compute.
// ============================================================================
template <int BM, int BN, int WM, int WN, int EPI>
__global__ __launch_bounds__((BM / WM) * (BN / WN) * 64)
void gemm_db_kernel(const f16* __restrict__ A, long long lda, long long Az,
                    const f16* __restrict__ Bw, long long ldb, long long Bz,
                    long long Bg, int NT,
                    const float* __restrict__ bias1, long long b1z,
                    const float* __restrict__ bias2, long long b2z,
                    const f16* __restrict__ addmat,
                    void* __restrict__ outp, long long out_z, long long ldo,
                    int rows_per_group) {
  constexpr int NW = (BM / WM) * (BN / WN);
  constexpr int FM = WM / 16, FN = WN / 16;
  constexpr int RA = BM / (NW * 16), RB = BN / (NW * 16);
  constexpr int LPT = RA + RB;
  const int tid = threadIdx.x, lane = tid & 63, wid = tid >> 6;
  const int bm0 = blockIdx.x * BM, bn0 = blockIdx.y * BN;
  const int z = blockIdx.z;
  const int gidx = (rows_per_group > 0) ? (bm0 / rows_per_group) : 0;

  __shared__ __align__(16) f16 As[4][BM * 32];
  __shared__ __align__(16) f16 Bs[4][BN * 32];

  const int wm0 = (wid / (BN / WN)) * WM;
  const int wn0 = (wid % (BN / WN)) * WN;
  const int srow = wid * 16 + (lane >> 2);
  const int scol = (lane & 3) * 8;
  const int fr = lane & 15, fq = lane >> 4;

  const f16* pa = A + (long long)z * Az + (long long)(bm0 + srow) * lda + scol;
  const f16* pb = Bw + (long long)z * Bz + (long long)gidx * Bg +
                  (long long)(bn0 + srow) * ldb + scol;
  const long long stA = (long long)(NW * 16) * lda;
  const long long stB = (long long)(NW * 16) * ldb;

  f32x4 acc[FM][FN] = {};

  auto stage = [&](int t) {
    const f16* qa = pa + t * 32;
    const f16* qb = pb + t * 32;
    const int b = t & 3;
    #pragma unroll
    for (int r = 0; r < RA; ++r)
      gl_lds16(qa + r * stA, &As[b][(r * NW + wid) * 512]);
    #pragma unroll
    for (int r = 0; r < RB; ++r)
      gl_lds16(qb + r * stB, &Bs[b][(r * NW + wid) * 512]);
  };
  auto comp = [&](int t) {
    const int b = t & 3;
    f16x8 af[FM], bf[FN];
    #pragma unroll
    for (int i = 0; i < FM; ++i)
      af[i] = *(const f16x8*)&As[b][(wm0 + i * 16 + fr) * 32 + fq * 8];
    #pragma unroll
    for (int j = 0; j < FN; ++j)
      bf[j] = *(const f16x8*)&Bs[b][(wn0 + j * 16 + fr) * 32 + fq * 8];
    #pragma unroll
    for (int i = 0; i < FM; ++i)
      #pragma unroll
      for (int j = 0; j < FN; ++j)
        acc[i][j] = __builtin_amdgcn_mfma_f32_16x16x32_f16(af[i], bf[j], acc[i][j], 0, 0, 0);
  };

  if (NT <= 4) {
    for (int t = 0; t < NT; ++t) stage(t);
    wvc<0>();
    BAR();
    for (int t = 0; t < NT; ++t) comp(t);
  } else {
    stage(0); stage(1); stage(2); stage(3);
    int t = 0;
    #pragma unroll 1
    for (; t < NT - 4; ++t) {
      wvc<3 * LPT>();
      BAR();
      comp(t);
      BAR();
      stage(t + 4);
    }
    wvc<3 * LPT>(); BAR(); comp(t); BAR(); ++t;
    wvc<2 * LPT>(); BAR(); comp(t); BAR(); ++t;
    wvc<1 * LPT>(); BAR(); comp(t); BAR(); ++t;
    wvc<0>();       BAR(); comp(t);
  }

  const float* b1p = bias1 ? bias1 + (long long)z * b1z : nullptr;
  const float* b2p = bias2 ? bias2 + (long long)gidx * b2z : nullptr;
  #pragma unroll
  for (int i = 0; i < FM; ++i) {
    #pragma unroll
    for (int j = 0; j < FN; ++j) {
      const int col = bn0 + wn0 + j * 16 + fr;
      const float b1 = b1p ? b1p[col] : 0.f;
      const float b2v = b2p ? ADAPT * b2p[col] : 0.f;
      #pragma unroll
      for (int r = 0; r < 4; ++r) {
        const int row = bm0 + wm0 + i * 16 + fq * 4 + r;
        float v = acc[i][j][r] + b1 + b2v;
        if constexpr (EPI == EPI_L0) {
          v += (float)addmat[(long long)(row & (B_ - 1)) * H_ + col];
          v = v > 0.f ? v : expm1f(v);
          ((f16*)outp)[(long long)row * ldo + col] = (f16)v;
        } else if constexpr (EPI == EPI_Z1) {
          ((f16*)outp)[(long long)z * out_z + (long long)row * ldo + col] = (f16)v;
        } else {  // EPI_OUT: group-major row -> [B, G, A] fp32
          const int g = row >> 10, b = row & 1023;
          ((float*)outp)[((long long)b * G_ + g) * A_ + col] = v;
        }
      }
    }
  }
}

extern "C" void kernel_launch(void* const* d_in, const int* in_sizes, int n_in,
                              void* d_out, int out_size, void* d_ws, size_t ws_size,
                              hipStream_t stream) {
  const float* s      = (const float*)d_in[0];
  const float* W_in   = (const float*)d_in[1];
  const float* b_in   = (const float*)d_in[2];
  const float* W_main = (const float*)d_in[3];
  const float* b_main = (const float*)d_in[4];
  const float* Wa     = (const float*)d_in[5];
  const float* ba     = (const float*)d_in[6];
  const float* Wb     = (const float*)d_in[7];
  const float* bb     = (const float*)d_in[8];
  const float* W_out  = (const float*)d_in[9];
  const float* b_out  = (const float*)d_in[10];

  char* ws = (char*)d_ws;
  size_t off = 0;
  auto alloc = [&](size_t bytes) -> void* {
    void* p = ws + off;
    off += (bytes + 255) & ~(size_t)255;
    return p;
  };
  f16* sh   = (f16*)alloc((size_t)B_ * S_ * 2);
  f16* Wint = (f16*)alloc((size_t)H_ * S_ * 2);
  f16* Wmt  = (f16*)alloc((size_t)L_ * H_ * H_ * 2);
  f16* Wat  = (f16*)alloc((size_t)L_ * G_ * R_ * H_ * 2);
  f16* Wbt  = (f16*)alloc((size_t)L_ * G_ * H_ * R_ * 2);
  f16* Wot  = (f16*)alloc((size_t)A_ * H_ * 2);
  f16* xh0  = (f16*)alloc((size_t)G_ * B_ * H_ * 2);
  f16* xh1  = (f16*)alloc((size_t)G_ * B_ * H_ * 2);
  f16* z1h  = (f16*)alloc((size_t)G_ * B_ * R_ * 2);
  f16* x0h  = xh1;                     // aliases: dead before xh1 first written
  f16* y0h  = xh1 + (size_t)B_ * H_;

  // all conversions/transposes in ONE launch
  prep_kernel<<<36352, dim3(32, 8), 0, stream>>>(
      s, sh, W_in, Wint, W_main, Wmt, Wa, Wat, Wb, Wbt, W_out, Wot);

  // x0 = s @ W_in + b_in  [B, H]; BM=32 -> 1024 blocks, high TLP
  gemm_db_kernel<32, 64, 32, 32, EPI_Z1><<<dim3(B_ / 32, H_ / 64, 1), 128, 0, stream>>>(
      sh, S_, 0, Wint, S_, 0, 0, S_ / 32,
      b_in, 0, nullptr, 0, nullptr, x0h, 0, H_, 0);

  // y0 = x0 @ W_main[0] + b_main[0]  [B, H]; BM=32 -> 1024 blocks
  gemm_db_kernel<32, 64, 32, 32, EPI_Z1><<<dim3(B_ / 32, H_ / 64, 1), 128, 0, stream>>>(
      x0h, H_, 0, Wmt, H_, 0, 0, H_ / 32,
      b_main, 0, nullptr, 0, nullptr, y0h, 0, H_, 0);

  // layer-0 z1[g] = x0 @ Wa[0,g] + ba[0,g]  (Az=0: shared x0); 512 blocks
  gemm_db_kernel<32, 64, 32, 32, EPI_Z1><<<dim3(B_ / 32, 1, G_), 128, 0, stream>>>(
      x0h, H_, 0, Wat, H_, (long long)R_ * H_, 0, H_ / 32,
      ba, R_, nullptr, 0, nullptr, z1h, (long long)B_ * R_, R_, 0);

  // layer-0 combine: x1 = elu(y0 + z1 @ (0.1*Wb[0,g]) + 0.1*bb[0,g]) -> [G,B,H]
  // BM=64 -> 49KB LDS -> 3 blocks/CU, 4096 blocks
  gemm_db_kernel<64, 128, 32, 64, EPI_L0><<<dim3(G_ * B_ / 64, H_ / 128, 1), 256, 0, stream>>>(
      z1h, R_, 0, Wbt, R_, 0, (long long)H_ * R_, R_ / 32,
      nullptr, 0, bb, H_, y0h, xh0, 0, H_, B_);

  f16* cur = xh0;
  f16* nxt = xh1;
  for (int l = 1; l < L_; ++l) {
    // z1[g] = x[g] @ Wa[l,g] + ba[l,g]; BM=32, 2-wave blocks (512 blocks, 2/CU)
    gemm_db_kernel<32, 64, 32, 32, EPI_Z1><<<dim3(B_ / 32, 1, G_), 128, 0, stream>>>(
        cur, H_, (long long)B_ * H_,
        Wat + (size_t)l * G_ * R_ * H_, H_, (long long)R_ * H_, 0, H_ / 32,
        ba + (size_t)l * G_ * R_, R_, nullptr, 0, nullptr,
        z1h, (long long)B_ * R_, R_, 0);
    // frozen 3-phase 256^2 main GEMM (supertile) with fused concat-K and ELU
    gemm8_main_kernel<<<512, 512, 0, stream>>>(
        cur, Wmt + (size_t)l * H_ * H_, z1h, Wbt + (size_t)l * G_ * H_ * R_,
        b_main + (size_t)l * H_, bb + (size_t)l * G_ * H_, nxt);
    f16* t = cur; cur = nxt; nxt = t;
  }

  // output: logits[b,g,:] = x @ W_out + b_out (fp32, permuted store)
  // BM=64 -> 512 blocks = 2/CU
  gemm_db_kernel<64, 128, 32, 64, EPI_OUT><<<dim3(G_ * B_ / 64, A_ / 128, 1), 256, 0, stream>>>(
      cur, H_, 0, Wot, H_, 0, 0, H_ / 32,
      b_out, 0, nullptr, 0, nullptr, d_out, 0, A_, 0);
}

// Round 17
// 697.129 us; speedup vs baseline: 1.0865x; 1.0079x over previous
//
#include <hip/hip_runtime.h>
#include <cstdint>
#include <cmath>

typedef _Float16 f16;
typedef _Float16 f16x2 __attribute__((ext_vector_type(2)));
typedef _Float16 f16x4 __attribute__((ext_vector_type(4)));
typedef _Float16 f16x8 __attribute__((ext_vector_type(8)));
typedef float f32x4 __attribute__((ext_vector_type(4)));

#define DEVI static __device__ __forceinline__

constexpr int B_ = 1024, S_ = 512, H_ = 2048, R_ = 64, G_ = 16, L_ = 4, A_ = 256;
constexpr float ADAPT = 0.1f;

// async global->LDS, 16B per lane. Dest is wave-uniform base + lane*16 (HW).
DEVI void gl_lds16(const void* g, void* l) {
  __builtin_amdgcn_global_load_lds((const __attribute__((address_space(1))) void*)g,
                                   (__attribute__((address_space(3))) void*)l,
                                   16, 0, 0);
}

template <int N> DEVI void wvc() {
  if constexpr (N == 0)       asm volatile("s_waitcnt vmcnt(0)");
  else if constexpr (N == 1)  asm volatile("s_waitcnt vmcnt(1)");
  else if constexpr (N == 2)  asm volatile("s_waitcnt vmcnt(2)");
  else if constexpr (N == 3)  asm volatile("s_waitcnt vmcnt(3)");
  else if constexpr (N == 4)  asm volatile("s_waitcnt vmcnt(4)");
  else if constexpr (N == 6)  asm volatile("s_waitcnt vmcnt(6)");
  else if constexpr (N == 8)  asm volatile("s_waitcnt vmcnt(8)");
  else if constexpr (N == 9)  asm volatile("s_waitcnt vmcnt(9)");
  else if constexpr (N == 12) asm volatile("s_waitcnt vmcnt(12)");
  else static_assert(N == 0, "unsupported vmcnt literal");
}

// ============================================================================
// prep_kernel: all input conversions in ONE launch.
// V2: 64x32 transpose patches; write phase stores f16x2 (4 B/lane) so the
// f16 output side is fully coalesced (was scalar 2 B/lane); s-cvt is
// float4 -> f16x4.
// ============================================================================
DEVI void tr64(float (*tile)[33], const float* __restrict__ src, f16* __restrict__ dst,
               int rows, int cols, float scale, int bid) {
  // block transposes input patch [r0, r0+64) x [c0, c0+32)
  const int nx = cols / 32, ny = rows / 64;
  const int z = bid / (nx * ny), rem = bid % (nx * ny);
  const int cy = rem / nx, cx = rem % nx;
  src += (size_t)z * rows * cols;
  dst += (size_t)z * rows * cols;
  const int tx = threadIdx.x, ty = threadIdx.y;
  const int r0 = cy * 64, c0 = cx * 32;
  #pragma unroll
  for (int i = ty; i < 64; i += 8)
    tile[i][tx] = src[(size_t)(r0 + i) * cols + (c0 + tx)];
  __syncthreads();
  #pragma unroll
  for (int j = ty; j < 32; j += 8) {
    f16x2 v;
    v.x = (f16)(tile[2 * tx][j] * scale);
    v.y = (f16)(tile[2 * tx + 1][j] * scale);
    *(f16x2*)&dst[(size_t)(c0 + j) * rows + r0 + 2 * tx] = v;
  }
}

__global__ void prep_kernel(const float* __restrict__ s, f16* __restrict__ sh,
                            const float* __restrict__ W_in, f16* __restrict__ Wint,
                            const float* __restrict__ W_main, f16* __restrict__ Wmt,
                            const float* __restrict__ Wa, f16* __restrict__ Wat,
                            const float* __restrict__ Wb, f16* __restrict__ Wbt,
                            const float* __restrict__ W_out, f16* __restrict__ Wot) {
  __shared__ float tile[64][33];
  int bid = blockIdx.x;
  if (bid < 512) {                // cvt s: 1024*512 = 512 blocks * 256 thr * 4
    int i = (bid * 256 + threadIdx.y * 32 + threadIdx.x) * 4;
    float4 v = *(const float4*)&s[i];
    f16x4 o;
    o.x = (f16)v.x; o.y = (f16)v.y; o.z = (f16)v.z; o.w = (f16)v.w;
    *(f16x4*)&sh[i] = o;
    return;
  }
  bid -= 512;
  if (bid < 512)  { tr64(tile, W_in,   Wint, S_, H_, 1.f,   bid); return; }   // 8*64
  bid -= 512;
  if (bid < 8192) { tr64(tile, W_main, Wmt,  H_, H_, 1.f,   bid); return; }   // 4*32*64
  bid -= 8192;
  if (bid < 4096) { tr64(tile, Wa,     Wat,  H_, R_, 1.f,   bid); return; }   // 64*32*2
  bid -= 4096;
  if (bid < 4096) { tr64(tile, Wb,     Wbt,  R_, H_, ADAPT, bid); return; }   // 64*1*64
  bid -= 4096;
  tr64(tile, W_out, Wot, H_, A_, 1.f, bid);                                   // 32*8
}

// ============================================================================
// Main 256x256 GEMM — 3-phase tile, supertile XCD swizzle (FETCH 281->103 MB).
//   Out = elu( Aacts[16384,2048] @ Wm^T + b1 + Z1[16384,64] @ (0.1*Wb)^T + 0.1*b2 )
// FROZEN: best measured 155 us; overlap rewrites regress (compiler lgkm).
// ============================================================================
#define MQ(QM, QN, AF, BF)                                                   \
  _Pragma("unroll") for (int i = 0; i < 4; ++i)                              \
  _Pragma("unroll") for (int j = 0; j < 2; ++j)                              \
  _Pragma("unroll") for (int k = 0; k < 2; ++k)                              \
    acc[QM][QN][i][j] = __builtin_amdgcn_mfma_f32_16x16x32_f16(              \
        AF[i][k], BF[j][k], acc[QM][QN][i][j], 0, 0, 0)

#define STGM(BASE, OFF, DST) do {                                            \
    gl_lds16(BASE + OFF, &lds[DST]);                                         \
    gl_lds16(BASE + OFF + 32768, &lds[DST + 1024]);                          \
    OFF += 128; DST ^= 65536; } while (0)
#define STGC(BASE, OFF, DST) do {                                            \
    gl_lds16(BASE + OFF, &lds[DST]);                                         \
    gl_lds16(BASE + OFF + 1024, &lds[DST + 1024]);                           \
    DST ^= 65536; } while (0)
#define NOSTG ((void)0)
#define WV4 asm volatile("s_waitcnt vmcnt(4)")
#define WV0 asm volatile("s_waitcnt vmcnt(0)")
#define NOW ((void)0)
#define BAR() __builtin_amdgcn_s_barrier()
#define PRI1 __builtin_amdgcn_s_setprio(1)
#define PRI0 __builtin_amdgcn_s_setprio(0)

#define TILE3(PC, S1a, S1b, S2a, S2b, BW) do {                               \
    f16x8 a0[4][2], a1[4][2], b0[2][2], b1v[2][2];                           \
    _Pragma("unroll") for (int i = 0; i < 4; ++i) {                          \
      a0[i][0] = *(const f16x8*)&lds[(PC) + cab + i * 2048 + lof0];          \
      a0[i][1] = *(const f16x8*)&lds[(PC) + cab + i * 2048 + lof1]; }        \
    _Pragma("unroll") for (int j = 0; j < 2; ++j) {                          \
      b0[j][0] = *(const f16x8*)&lds[(PC) + cbb + j * 2048 + lof0];          \
      b0[j][1] = *(const f16x8*)&lds[(PC) + cbb + j * 2048 + lof1]; }        \
    S1a; S1b; BAR();                                                         \
    PRI1; MQ(0, 0, a0, b0); PRI0; BAR();                                     \
    _Pragma("unroll") for (int j = 0; j < 2; ++j) {                          \
      b1v[j][0] = *(const f16x8*)&lds[(PC) + cbb + 16384 + j * 2048 + lof0]; \
      b1v[j][1] = *(const f16x8*)&lds[(PC) + cbb + 16384 + j * 2048 + lof1]; } \
    S2a; S2b; BAR();                                                         \
    PRI1; MQ(0, 1, a0, b1v); PRI0; BAR();                                    \
    _Pragma("unroll") for (int i = 0; i < 4; ++i) {                          \
      a1[i][0] = *(const f16x8*)&lds[(PC) + cab + 16384 + i * 2048 + lof0];  \
      a1[i][1] = *(const f16x8*)&lds[(PC) + cab + 16384 + i * 2048 + lof1]; } \
    BAR();                                                                   \
    PRI1; MQ(1, 1, a1, b1v); MQ(1, 0, a1, b0); PRI0;                         \
    BW; BAR();                                                               \
  } while (0)

__global__ __launch_bounds__(512, 2)
void gemm8_main_kernel(const f16* __restrict__ Aacts,   // [16384][2048]
                      const f16* __restrict__ Wm,       // [2048][2048] W_main^T
                      const f16* __restrict__ Z1,       // [16384][64]
                      const f16* __restrict__ Wb2,      // [G][2048][64] 0.1*Wb^T
                      const float* __restrict__ b1,     // [2048]
                      const float* __restrict__ b2,     // [G][2048]
                      f16* __restrict__ Out) {          // [16384][2048]
  __shared__ __align__(16) char lds[131072];
  const int tid = threadIdx.x, lane = tid & 63, wid = tid >> 6;
  // supertile: XCD x owns bm in [8x, 8x+8), all bn -> per-XCD set A 8MB + W 4MB
  const int x = blockIdx.x & 7, local = blockIdx.x >> 3;
  const int bm0 = (x * 8 + (local & 7)) * 256, bn0 = (local >> 3) * 256;
  const int g = bm0 >> 10;
  const char* GA = (const char*)Aacts;
  const char* GB = (const char*)Wm;
  const char* GZ = (const char*)Z1;
  const char* GW2 = (const char*)(Wb2 + (size_t)g * H_ * R_);
  const float* b2g = b2 + (size_t)g * H_;

  const int srow8 = lane >> 3;
  const int scolb = ((lane & 7) ^ srow8) * 16;
  const int fr = lane & 15, fq = lane >> 4;
  const uint32_t lof0 = fr * 128 + ((fq * 16) ^ ((fr & 7) << 4));
  const uint32_t lof1 = lof0 ^ 64;

  const uint32_t rA0 = bm0 + wid * 16 + srow8;
  const uint32_t rB0 = bn0 + wid * 16 + srow8;
  uint32_t oA0 = rA0 * 4096 + scolb;
  uint32_t oA1 = oA0 + 128 * 4096;
  uint32_t oB0 = rB0 * 4096 + scolb;
  uint32_t oB1 = oB0 + 128 * 4096;
  uint32_t dA0 = wid * 2048;
  uint32_t dA1 = 16384 + wid * 2048;
  uint32_t dB0 = 32768 + wid * 2048;
  uint32_t dB1 = 49152 + wid * 2048;
  const uint32_t cab = (wid >> 2) * 8192;
  const uint32_t cbb = 32768 + (wid & 3) * 4096;

  f32x4 acc[2][2][4][2] = {};   // [Qm][Qn][i][j]

  // prologue: tile0 full (A0,B0,A1,B1) + tile1's A0,B0 = 12 loads; retire tile0.
  STGM(GA, oA0, dA0);
  STGM(GB, oB0, dB0);
  STGM(GA, oA1, dA1);
  STGM(GB, oB1, dB1);
  STGM(GA, oA0, dA0);
  STGM(GB, oB0, dB0);
  WV4;
  BAR();

  uint32_t oA0c = rA0 * 128 + scolb;
  uint32_t oA1c = oA0c + 128 * 128;
  uint32_t oB0c = rB0 * 128 + scolb;
  uint32_t oB1c = oB0c + 128 * 128;

  // steady: tiles 0..29
  #pragma unroll 1
  for (int it = 0; it < 15; ++it) {
    TILE3(0,
          STGM(GB, oB1, dB1), STGM(GA, oA1, dA1),
          STGM(GA, oA0, dA0), STGM(GB, oB0, dB0), WV4);
    TILE3(65536,
          STGM(GB, oB1, dB1), STGM(GA, oA1, dA1),
          STGM(GA, oA0, dA0), STGM(GB, oB0, dB0), WV4);
  }
  // t=30: P1 stages B1/A1(31) main; P2 stages A0/B0(32) = concat (128B rows)
  TILE3(0,
        STGM(GB, oB1, dB1), STGM(GA, oA1, dA1),
        STGC(GZ, oA0c, dA0), STGC(GW2, oB0c, dB0), WV4);
  // t=31: P1 stages B1/A1(32) concat; drain all at end
  TILE3(65536,
        STGC(GW2, oB1c, dB1), STGC(GZ, oA1c, dA1),
        NOSTG, NOSTG, WV0);
  // t=32: concat compute only
  TILE3(0, NOSTG, NOSTG, NOSTG, NOSTG, NOW);

  // epilogue: v = acc + b1[col] + 0.1*b2[col]; ELU; f16 store
  #pragma unroll
  for (int Qn = 0; Qn < 2; ++Qn) {
    #pragma unroll
    for (int j = 0; j < 2; ++j) {
      const int col = bn0 + Qn * 128 + (wid & 3) * 32 + j * 16 + fr;
      const float bb1 = b1[col];
      const float bb2 = ADAPT * b2g[col];
      #pragma unroll
      for (int Qm = 0; Qm < 2; ++Qm)
        #pragma unroll
        for (int i = 0; i < 4; ++i)
          #pragma unroll
          for (int r = 0; r < 4; ++r) {
            const int row = bm0 + Qm * 128 + (wid >> 2) * 64 + i * 16 + fq * 4 + r;
            float v = acc[Qm][Qn][i][j][r] + bb1 + bb2;
            v = v > 0.f ? v : expm1f(v);
            Out[(size_t)row * H_ + col] = (f16)v;
          }
    }
  }
}

enum { EPI_Z1 = 0, EPI_OUT = 1, EPI_L0 = 2 };

// ============================================================================
// Small/odd-shape GEMM with 4-deep ring-buffer pipeline (counted vmcnt). BK=32.
// TLP discipline: keep >=2 blocks/CU (small BM, small LDS) so one block's
// vmcnt+barrier waits hide under another's compute.
// ============================================================================
template <int BM, int BN, int WM, int WN, int EPI>
__global__ __launch_bounds__((BM / WM) * (BN / WN) * 64)
void gemm_db_kernel(const f16* __restrict__ A, long long lda, long long Az,
                    const f16* __restrict__ Bw, long long ldb, long long Bz,
                    long long Bg, int NT,
                    const float* __restrict__ bias1, long long b1z,
                    const float* __restrict__ bias2, long long b2z,
                    const f16* __restrict__ addmat,
                    void* __restrict__ outp, long long out_z, long long ldo,
                    int rows_per_group) {
  constexpr int NW = (BM / WM) * (BN / WN);
  constexpr int FM = WM / 16, FN = WN / 16;
  constexpr int RA = BM / (NW * 16), RB = BN / (NW * 16);
  constexpr int LPT = RA + RB;
  const int tid = threadIdx.x, lane = tid & 63, wid = tid >> 6;
  const int bm0 = blockIdx.x * BM, bn0 = blockIdx.y * BN;
  const int z = blockIdx.z;
  const int gidx = (rows_per_group > 0) ? (bm0 / rows_per_group) : 0;

  __shared__ __align__(16) f16 As[4][BM * 32];
  __shared__ __align__(16) f16 Bs[4][BN * 32];

  const int wm0 = (wid / (BN / WN)) * WM;
  const int wn0 = (wid % (BN / WN)) * WN;
  const int srow = wid * 16 + (lane >> 2);
  const int scol = (lane & 3) * 8;
  const int fr = lane & 15, fq = lane >> 4;

  const f16* pa = A + (long long)z * Az + (long long)(bm0 + srow) * lda + scol;
  const f16* pb = Bw + (long long)z * Bz + (long long)gidx * Bg +
                  (long long)(bn0 + srow) * ldb + scol;
  const long long stA = (long long)(NW * 16) * lda;
  const long long stB = (long long)(NW * 16) * ldb;

  f32x4 acc[FM][FN] = {};

  auto stage = [&](int t) {
    const f16* qa = pa + t * 32;
    const f16* qb = pb + t * 32;
    const int b = t & 3;
    #pragma unroll
    for (int r = 0; r < RA; ++r)
      gl_lds16(qa + r * stA, &As[b][(r * NW + wid) * 512]);
    #pragma unroll
    for (int r = 0; r < RB; ++r)
      gl_lds16(qb + r * stB, &Bs[b][(r * NW + wid) * 512]);
  };
  auto comp = [&](int t) {
    const int b = t & 3;
    f16x8 af[FM], bf[FN];
    #pragma unroll
    for (int i = 0; i < FM; ++i)
      af[i] = *(const f16x8*)&As[b][(wm0 + i * 16 + fr) * 32 + fq * 8];
    #pragma unroll
    for (int j = 0; j < FN; ++j)
      bf[j] = *(const f16x8*)&Bs[b][(wn0 + j * 16 + fr) * 32 + fq * 8];
    #pragma unroll
    for (int i = 0; i < FM; ++i)
      #pragma unroll
      for (int j = 0; j < FN; ++j)
        acc[i][j] = __builtin_amdgcn_mfma_f32_16x16x32_f16(af[i], bf[j], acc[i][j], 0, 0, 0);
  };

  if (NT <= 4) {
    for (int t = 0; t < NT; ++t) stage(t);
    wvc<0>();
    BAR();
    for (int t = 0; t < NT; ++t) comp(t);
  } else {
    stage(0); stage(1); stage(2); stage(3);
    int t = 0;
    #pragma unroll 1
    for (; t < NT - 4; ++t) {
      wvc<3 * LPT>();
      BAR();
      comp(t);
      BAR();
      stage(t + 4);
    }
    wvc<3 * LPT>(); BAR(); comp(t); BAR(); ++t;
    wvc<2 * LPT>(); BAR(); comp(t); BAR(); ++t;
    wvc<1 * LPT>(); BAR(); comp(t); BAR(); ++t;
    wvc<0>();       BAR(); comp(t);
  }

  const float* b1p = bias1 ? bias1 + (long long)z * b1z : nullptr;
  const float* b2p = bias2 ? bias2 + (long long)gidx * b2z : nullptr;
  #pragma unroll
  for (int i = 0; i < FM; ++i) {
    #pragma unroll
    for (int j = 0; j < FN; ++j) {
      const int col = bn0 + wn0 + j * 16 + fr;
      const float b1 = b1p ? b1p[col] : 0.f;
      const float b2v = b2p ? ADAPT * b2p[col] : 0.f;
      #pragma unroll
      for (int r = 0; r < 4; ++r) {
        const int row = bm0 + wm0 + i * 16 + fq * 4 + r;
        float v = acc[i][j][r] + b1 + b2v;
        if constexpr (EPI == EPI_L0) {
          v += (float)addmat[(long long)(row & (B_ - 1)) * H_ + col];
          v = v > 0.f ? v : expm1f(v);
          ((f16*)outp)[(long long)row * ldo + col] = (f16)v;
        } else if constexpr (EPI == EPI_Z1) {
          ((f16*)outp)[(long long)z * out_z + (long long)row * ldo + col] = (f16)v;
        } else {  // EPI_OUT: group-major row -> [B, G, A] fp32
          const int g = row >> 10, b = row & 1023;
          ((float*)outp)[((long long)b * G_ + g) * A_ + col] = v;
        }
      }
    }
  }
}

extern "C" void kernel_launch(void* const* d_in, const int* in_sizes, int n_in,
                              void* d_out, int out_size, void* d_ws, size_t ws_size,
                              hipStream_t stream) {
  const float* s      = (const float*)d_in[0];
  const float* W_in   = (const float*)d_in[1];
  const float* b_in   = (const float*)d_in[2];
  const float* W_main = (const float*)d_in[3];
  const float* b_main = (const float*)d_in[4];
  const float* Wa     = (const float*)d_in[5];
  const float* ba     = (const float*)d_in[6];
  const float* Wb     = (const float*)d_in[7];
  const float* bb     = (const float*)d_in[8];
  const float* W_out  = (const float*)d_in[9];
  const float* b_out  = (const float*)d_in[10];

  char* ws = (char*)d_ws;
  size_t off = 0;
  auto alloc = [&](size_t bytes) -> void* {
    void* p = ws + off;
    off += (bytes + 255) & ~(size_t)255;
    return p;
  };
  f16* sh   = (f16*)alloc((size_t)B_ * S_ * 2);
  f16* Wint = (f16*)alloc((size_t)H_ * S_ * 2);
  f16* Wmt  = (f16*)alloc((size_t)L_ * H_ * H_ * 2);
  f16* Wat  = (f16*)alloc((size_t)L_ * G_ * R_ * H_ * 2);
  f16* Wbt  = (f16*)alloc((size_t)L_ * G_ * H_ * R_ * 2);
  f16* Wot  = (f16*)alloc((size_t)A_ * H_ * 2);
  f16* xh0  = (f16*)alloc((size_t)G_ * B_ * H_ * 2);
  f16* xh1  = (f16*)alloc((size_t)G_ * B_ * H_ * 2);
  f16* z1h  = (f16*)alloc((size_t)G_ * B_ * R_ * 2);
  f16* x0h  = xh1;                     // aliases: dead before xh1 first written
  f16* y0h  = xh1 + (size_t)B_ * H_;

  // all conversions/transposes in ONE launch (coalesced-write V2: 17664 blocks)
  prep_kernel<<<17664, dim3(32, 8), 0, stream>>>(
      s, sh, W_in, Wint, W_main, Wmt, Wa, Wat, Wb, Wbt, W_out, Wot);

  // x0 = s @ W_in + b_in  [B, H]; BM=32 -> 1024 blocks, high TLP
  gemm_db_kernel<32, 64, 32, 32, EPI_Z1><<<dim3(B_ / 32, H_ / 64, 1), 128, 0, stream>>>(
      sh, S_, 0, Wint, S_, 0, 0, S_ / 32,
      b_in, 0, nullptr, 0, nullptr, x0h, 0, H_, 0);

  // y0 = x0 @ W_main[0] + b_main[0]  [B, H]; BM=32 -> 1024 blocks
  gemm_db_kernel<32, 64, 32, 32, EPI_Z1><<<dim3(B_ / 32, H_ / 64, 1), 128, 0, stream>>>(
      x0h, H_, 0, Wmt, H_, 0, 0, H_ / 32,
      b_main, 0, nullptr, 0, nullptr, y0h, 0, H_, 0);

  // layer-0 z1[g] = x0 @ Wa[0,g] + ba[0,g]  (Az=0: shared x0); 512 blocks
  gemm_db_kernel<32, 64, 32, 32, EPI_Z1><<<dim3(B_ / 32, 1, G_), 128, 0, stream>>>(
      x0h, H_, 0, Wat, H_, (long long)R_ * H_, 0, H_ / 32,
      ba, R_, nullptr, 0, nullptr, z1h, (long long)B_ * R_, R_, 0);

  // layer-0 combine: x1 = elu(y0 + z1 @ (0.1*Wb[0,g]) + 0.1*bb[0,g]) -> [G,B,H]
  // BM=64 -> 49KB LDS -> 3 blocks/CU, 4096 blocks
  gemm_db_kernel<64, 128, 32, 64, EPI_L0><<<dim3(G_ * B_ / 64, H_ / 128, 1), 256, 0, stream>>>(
      z1h, R_, 0, Wbt, R_, 0, (long long)H_ * R_, R_ / 32,
      nullptr, 0, bb, H_, y0h, xh0, 0, H_, B_);

  f16* cur = xh0;
  f16* nxt = xh1;
  for (int l = 1; l < L_; ++l) {
    // z1[g] = x[g] @ Wa[l,g] + ba[l,g]; BM=32, 2-wave blocks (512 blocks, 2/CU)
    gemm_db_kernel<32, 64, 32, 32, EPI_Z1><<<dim3(B_ / 32, 1, G_), 128, 0, stream>>>(
        cur, H_, (long long)B_ * H_,
        Wat + (size_t)l * G_ * R_ * H_, H_, (long long)R_ * H_, 0, H_ / 32,
        ba + (size_t)l * G_ * R_, R_, nullptr, 0, nullptr,
        z1h, (long long)B_ * R_, R_, 0);
    // frozen 3-phase 256^2 main GEMM (supertile) with fused concat-K and ELU
    gemm8_main_kernel<<<512, 512, 0, stream>>>(
        cur, Wmt + (size_t)l * H_ * H_, z1h, Wbt + (size_t)l * G_ * H_ * R_,
        b_main + (size_t)l * H_, bb + (size_t)l * G_ * H_, nxt);
    f16* t = cur; cur = nxt; nxt = t;
  }

  // output: logits[b,g,:] = x @ W_out + b_out (fp32, permuted store)
  // BM=64 -> 512 blocks = 2/CU
  gemm_db_kernel<64, 128, 32, 64, EPI_OUT><<<dim3(G_ * B_ / 64, A_ / 128, 1), 256, 0, stream>>>(
      cur, H_, 0, Wot, H_, 0, 0, H_ / 32,
      b_out, 0, nullptr, 0, nullptr, d_out, 0, A_, 0);
}